// Round 8
// baseline (223.833 us; speedup 1.0000x reference)
//
#include <hip/hip_runtime.h>
#include <hip/hip_bf16.h>

typedef unsigned short u16;
typedef unsigned int u32;
typedef short bf16x8 __attribute__((ext_vector_type(8)));
typedef float f32x4 __attribute__((ext_vector_type(4)));

#define DM 1024
#define SEQ 2048
#define MTOK 8192   // 4*2048
#define NQKV 3072

// 0.125 * log2(e): scores land in log2 domain -> exp2f is a single v_exp_f32
#define QSCALE 0.18033688011112042f

#define BAR() __builtin_amdgcn_s_barrier()
#define VMW(n) asm volatile("s_waitcnt vmcnt(" #n ")" ::: "memory")

__device__ __forceinline__ u16 f2bf(float f) {
  union { float f; unsigned u; } a; a.f = f;
  unsigned r = a.u + 0x7FFFu + ((a.u >> 16) & 1u);
  return (u16)(r >> 16);
}

__device__ __forceinline__ u32 cvt2(float a, float b) {
  __hip_bfloat162 t = __float22bfloat162_rn(make_float2(a, b));
  u32 r; __builtin_memcpy(&r, &t, 4); return r;
}

__device__ __forceinline__ void gload_lds16(const u16* g, u16* l) {
  __builtin_amdgcn_global_load_lds(
      (const __attribute__((address_space(1))) unsigned int*)g,
      (__attribute__((address_space(3))) unsigned int*)l, 16, 0, 0);
}

// ---------------- cast x (fp32 -> bf16), vectorized ----------------
__global__ __launch_bounds__(256) void cast_x_kernel(const float* __restrict__ in,
                                                     u16* __restrict__ out) {
  int i = blockIdx.x * 256 + threadIdx.x;
  float4 v = ((const float4*)in)[i];
  ushort4 o;
  o.x = f2bf(v.x); o.y = f2bf(v.y); o.z = f2bf(v.z); o.w = f2bf(v.w);
  ((ushort4*)out)[i] = o;
}

// ---------------- transpose + cast: in [R][C] fp32 -> out [C][R] bf16 ----------------
__global__ __launch_bounds__(256) void transpose_cast_kernel(const float* __restrict__ in,
                                                             u16* __restrict__ out,
                                                             int R, int C) {
  __shared__ float tile[32][33];
  const int tx = threadIdx.x & 31, ty = threadIdx.x >> 5;
  const int r0 = blockIdx.y << 5, c0 = blockIdx.x << 5;
#pragma unroll
  for (int i = 0; i < 32; i += 8)
    tile[ty + i][tx] = in[(size_t)(r0 + ty + i) * C + (c0 + tx)];
  __syncthreads();
#pragma unroll
  for (int i = 0; i < 32; i += 8)
    out[(size_t)(c0 + ty + i) * R + (r0 + tx)] = f2bf(tile[tx][ty + i]);
}

// ---------------- fill V^T pad rows: row 64 = ones (row-sum row), 65..79 = 0 ----------
__global__ __launch_bounds__(256) void fill_vpad_kernel(u16* __restrict__ vT) {
  const int i = blockIdx.x * 256 + threadIdx.x;   // 524288 ushort4 slots
  const int col4 = i & (SEQ / 4 - 1);
  const int rowg = i >> 9;                        // bh*16 + r
  const int bh = rowg >> 4, r = rowg & 15;
  const u16 val = (r == 0) ? (u16)0x3F80 : (u16)0;
  ushort4 o; o.x = val; o.y = val; o.z = val; o.w = val;
  ((ushort4*)(vT + ((size_t)bh * 80 + 64 + r) * SEQ))[col4] = o;
}

// ============== QKV GEMM: 256x256 tile, BK=64, 8-phase counted-vmcnt ==============
// A[8192][1024] bf16 @ Bt[3072][1024]^T. 8 waves (2M x 4N), 512 threads.
// LDS: 2 bufs x (A 256x64 + B 256x64) bf16 = 128 KB. Chunk swizzle: phys = c ^ (row&7),
// dest linear (global_load_lds), source pre-swizzled, reads swizzled.
// Stage units per K-tile (2 loads/thread each): UB0(B rows 0-127), UB1(B 128-255),
// UAm0(A rows 0-63 & 128-191), UAm1(A 64-127 & 192-255).
// Schedule per iteration I (tiles t=2I in buf0 @p0-3, t+1 in buf1 @p4-7):
//   p0..p3 stage buf1<-t+1 (UB0,UB1,UAm0,UAm1); p4..p7 stage buf0<-t+2.
//   vmcnt(4) end-p1, vmcnt(2) end-p3, vmcnt(4) end-p5, vmcnt(2) end-p7 (never 0).
__global__ __launch_bounds__(512, 2) void gemm8_qkv_kernel(
    const u16* __restrict__ A, const u16* __restrict__ Bt,
    const float* __restrict__ bias,
    u16* __restrict__ oq, u16* __restrict__ ok, u16* __restrict__ ovT) {
  __shared__ alignas(16) u16 As8[2 * 256 * 64];   // 64 KB
  __shared__ alignas(16) u16 Bs8[2 * 256 * 64];   // 64 KB

  const int tid = threadIdx.x;
  const int lane = tid & 63;
  const int wid = tid >> 6;
  const int wm = wid >> 2, wn = wid & 3;
  const int l15 = lane & 15, l4 = lane >> 4;
  const int swz = l15 & 7;

  // XCD-aware mapping: each XCD owns 4 row-panels x all 12 col-blocks
  const int bid = blockIdx.x;
  const int xcd = bid & 7, idx = bid >> 3;        // idx 0..47
  const int brow = (xcd << 2) + idx / 12;
  const int bcol = idx % 12;
  const int row0 = brow << 8, col0 = bcol << 8;

  const int st_r = tid >> 3, st_c = tid & 7;
  const int st_sw = ((st_c ^ (st_r & 7)) << 3);   // pre-swizzled source chunk offset (u16)

  f32x4 acc[8][4];
#pragma unroll
  for (int m = 0; m < 8; ++m)
#pragma unroll
    for (int n = 0; n < 4; ++n) acc[m][n] = (f32x4){0.f, 0.f, 0.f, 0.f};

  auto stageA = [&](int buf, int kt, int half) {
#pragma unroll
    for (int j = 0; j < 2; ++j) {
      const int r = (j << 7) + (half << 6) + st_r;
      gload_lds16(A + (size_t)(row0 + r) * 1024 + (kt << 6) + st_sw,
                  As8 + (buf << 14) + r * 64 + (st_c << 3));
    }
  };
  auto stageB = [&](int buf, int kt, int half) {
#pragma unroll
    for (int j = 0; j < 2; ++j) {
      const int r = (half << 7) + (j << 6) + st_r;
      gload_lds16(Bt + (size_t)(col0 + r) * 1024 + (kt << 6) + st_sw,
                  Bs8 + (buf << 14) + r * 64 + (st_c << 3));
    }
  };

  bf16x8 af[4][2], bf0[2][2], bf1[2][2];

  auto rdA = [&](int buf, int mh) {
    const u16* base = As8 + (buf << 14) + ((wm << 7) + (mh << 6) + l15) * 64;
#pragma unroll
    for (int mf = 0; mf < 4; ++mf)
#pragma unroll
      for (int ks = 0; ks < 2; ++ks) {
        const int c = (ks << 2) + l4;
        af[mf][ks] = *(const bf16x8*)(base + (mf << 4) * 64 + ((c ^ swz) << 3));
      }
  };
  auto rdB = [&](bf16x8 (&bf)[2][2], int buf, int nh) {
    const u16* base = Bs8 + (buf << 14) + ((wn << 6) + (nh << 5) + l15) * 64;
#pragma unroll
    for (int nfl = 0; nfl < 2; ++nfl)
#pragma unroll
      for (int ks = 0; ks < 2; ++ks) {
        const int c = (ks << 2) + l4;
        bf[nfl][ks] = *(const bf16x8*)(base + (nfl << 4) * 64 + ((c ^ swz) << 3));
      }
  };
  auto mm = [&](bf16x8 (&bf)[2][2], int mh, int nh) {
    __builtin_amdgcn_s_setprio(1);
#pragma unroll
    for (int mf = 0; mf < 4; ++mf)
#pragma unroll
      for (int nfl = 0; nfl < 2; ++nfl)
#pragma unroll
        for (int ks = 0; ks < 2; ++ks)
          acc[(mh << 2) + mf][(nh << 1) + nfl] = __builtin_amdgcn_mfma_f32_16x16x32_bf16(
              af[mf][ks], bf[nfl][ks], acc[(mh << 2) + mf][(nh << 1) + nfl], 0, 0, 0);
    __builtin_amdgcn_s_setprio(0);
  };

  // ---- prologue: tile 0 -> buf0 ----
  stageB(0, 0, 0); stageB(0, 0, 1); stageA(0, 0, 0); stageA(0, 0, 1);
  VMW(2);                 // UB0,UB1,UAm0 landed
  BAR();

  // ---- main loop: iterations 0..6 (tiles 0..13), all stages in-range ----
#pragma unroll 1
  for (int I = 0; I < 7; ++I) {
    const int t1 = 2 * I + 1, t2 = 2 * I + 2;
    // p0
    rdA(0, 0); rdB(bf0, 0, 0); stageB(1, t1, 0);
    BAR(); mm(bf0, 0, 0); BAR();
    // p1
    rdB(bf1, 0, 1); stageB(1, t1, 1);
    BAR(); mm(bf1, 0, 1); VMW(4); BAR();
    // p2
    rdA(0, 1); stageA(1, t1, 0);
    BAR(); mm(bf0, 1, 0); BAR();
    // p3
    stageA(1, t1, 1);
    BAR(); mm(bf1, 1, 1); VMW(2); BAR();
    // p4
    rdA(1, 0); rdB(bf0, 1, 0); stageB(0, t2, 0);
    BAR(); mm(bf0, 0, 0); BAR();
    // p5
    rdB(bf1, 1, 1); stageB(0, t2, 1);
    BAR(); mm(bf1, 0, 1); VMW(4); BAR();
    // p6
    rdA(1, 1); stageA(0, t2, 0);
    BAR(); mm(bf0, 1, 0); BAR();
    // p7
    stageA(0, t2, 1);
    BAR(); mm(bf1, 1, 1); VMW(2); BAR();
  }

  // ---- epilogue iteration: tiles 14 (buf0) and 15 (buf1); no t+2 stages ----
  // p0
  rdA(0, 0); rdB(bf0, 0, 0); stageB(1, 15, 0);
  BAR(); mm(bf0, 0, 0); BAR();
  // p1
  rdB(bf1, 0, 1); stageB(1, 15, 1);
  BAR(); mm(bf1, 0, 1); VMW(4); BAR();
  // p2
  rdA(0, 1); stageA(1, 15, 0);
  BAR(); mm(bf0, 1, 0); BAR();
  // p3
  stageA(1, 15, 1);
  BAR(); mm(bf1, 1, 1); VMW(2); BAR();
  // p4
  rdA(1, 0); rdB(bf0, 1, 0);
  BAR(); mm(bf0, 0, 0); BAR();
  // p5
  rdB(bf1, 1, 1);
  BAR(); mm(bf1, 0, 1); VMW(0); BAR();
  // p6
  rdA(1, 1);
  BAR(); mm(bf0, 1, 0); BAR();
  // p7
  BAR(); mm(bf1, 1, 1); BAR();

  // ---- epilogue: scatter q (scaled), k, vT with bias ----
#pragma unroll
  for (int nf = 0; nf < 4; ++nf) {
    const int col = col0 + (wn << 6) + (nf << 4) + l15;
    const float bv = bias[col];
    const int sel = col >> 10;
    const int hh = (col & 1023) >> 6;
    const int d = col & 63;
    const float scl = (sel == 0) ? QSCALE : 1.0f;
#pragma unroll
    for (int mf = 0; mf < 8; ++mf)
#pragma unroll
      for (int r = 0; r < 4; ++r) {
        const int row = row0 + (wm << 7) + (mf << 4) + (l4 << 2) + r;
        const int bb = row >> 11, s = row & 2047;
        const u16 v = f2bf((acc[mf][nf][r] + bv) * scl);
        const int bh = (bb << 4) + hh;
        if (sel == 0)      oq[((size_t)bh * SEQ + s) * 64 + d] = v;
        else if (sel == 1) ok[((size_t)bh * SEQ + s) * 64 + d] = v;
        else               ovT[((size_t)bh * 80 + d) * SEQ + s] = v;
      }
  }
}

// ---------------- out-proj GEMM: A[M][1024] bf16 @ Bt[N][1024]^T, 128x128 tile -------
__global__ __launch_bounds__(256) void gemm_out_kernel(
    const u16* __restrict__ A, const u16* __restrict__ Bt,
    const float* __restrict__ bias, float* __restrict__ of, int N) {
  const int K = 1024;
  __shared__ alignas(16) u16 As[128 * 32];
  __shared__ alignas(16) u16 Bs[128 * 32];
  const int tid = threadIdx.x;
  const int lane = tid & 63, wid = tid >> 6;
  const int wr = wid >> 1, wc = wid & 1;
  const int l15 = lane & 15, l4 = lane >> 4;
  const int row0 = blockIdx.y << 7, col0 = blockIdx.x << 7;

  f32x4 acc[4][4];
#pragma unroll
  for (int m = 0; m < 4; ++m)
#pragma unroll
    for (int n = 0; n < 4; ++n) acc[m][n] = (f32x4){0.f, 0.f, 0.f, 0.f};

  for (int kt = 0; kt < K; kt += 32) {
    __syncthreads();
#pragma unroll
    for (int i = 0; i < 2; ++i) {
      const int tt = tid + (i << 8);
      const int r = tt >> 2, kk = (tt & 3) << 3;
      gload_lds16(A + (size_t)(row0 + r) * K + kt + kk, As + tt * 8);
      gload_lds16(Bt + (size_t)(col0 + r) * K + kt + kk, Bs + tt * 8);
    }
    __syncthreads();
    bf16x8 a[4], b[4];
#pragma unroll
    for (int m = 0; m < 4; ++m)
      a[m] = *(const bf16x8*)(As + ((wr << 6) + (m << 4) + l15) * 32 + (l4 << 3));
#pragma unroll
    for (int n = 0; n < 4; ++n)
      b[n] = *(const bf16x8*)(Bs + ((wc << 6) + (n << 4) + l15) * 32 + (l4 << 3));
#pragma unroll
    for (int m = 0; m < 4; ++m)
#pragma unroll
      for (int n = 0; n < 4; ++n)
        acc[m][n] = __builtin_amdgcn_mfma_f32_16x16x32_bf16(a[m], b[n], acc[m][n], 0, 0, 0);
  }

#pragma unroll
  for (int n = 0; n < 4; ++n) {
    const int col = col0 + (wc << 6) + (n << 4) + l15;
    const float bv = bias[col];
#pragma unroll
    for (int m = 0; m < 4; ++m)
#pragma unroll
      for (int r = 0; r < 4; ++r) {
        const int row = row0 + (wr << 6) + (m << 4) + (l4 << 2) + r;
        of[(size_t)row * N + col] = acc[m][n][r] + bv;
      }
  }
}

// ---------------- flash attention: 8 waves/block, K/V staged in LDS -----------------
__global__ __launch_bounds__(512, 4) void attn_kernel(const u16* __restrict__ qb,
                                                      const u16* __restrict__ kbuf,
                                                      const u16* __restrict__ vT,
                                                      u16* __restrict__ zb) {
  __shared__ alignas(16) u16 Ks[2][64 * 64];   // 16 KB
  __shared__ alignas(16) u16 Vs[2][80 * 64];   // 20 KB
  __shared__ alignas(16) u16 Ps[8][32 * 64];   // 32 KB

  const int bid = blockIdx.x;
  const int xcd = bid & 7;
  const int idx = bid >> 3;
  const int bh = (xcd << 3) | (idx & 7);        // 8 bh per XCD
  const int qpart = idx >> 3;                   // 0..7
  const int qseg = (qpart < 4) ? (7 - qpart) : (qpart - 4);  // CU pairs sum to 7
  const int b = bh >> 4, h = bh & 15;

  const int tid = threadIdx.x;
  const int lane = tid & 63, wid = tid >> 6;
  const int l15 = lane & 15, l4 = lane >> 4;
  const int swz = l15 & 7;

  const u16* qp = qb + (size_t)bh * SEQ * 64;
  const u16* kp = kbuf + (size_t)bh * SEQ * 64;
  const u16* vp = vT + (size_t)bh * 80 * SEQ;

  const int qw0 = qseg * 256 + (wid << 5);      // this wave's first q row
  const int nkt = (qseg + 1) << 2;              // block k-tiles
  const int ktmax = (qseg << 2) + (wid >> 1);   // this wave's diagonal tile

  const int srow = tid >> 3, schk = tid & 7;
  const u16* ksrc  = kp + (size_t)srow * 64 + ((schk ^ (srow & 7)) << 3);
  const u16* vsrc  = vp + (size_t)srow * SEQ + ((schk ^ (srow & 7)) << 3);
  const u16* vsrc2 = vp + (size_t)(64 + srow) * SEQ + ((schk ^ (srow & 7)) << 3);

  auto stage = [&](int buf, int kt) {
    gload_lds16(ksrc + (size_t)kt * 4096, &Ks[buf][0] + tid * 8);
    gload_lds16(vsrc + (size_t)kt * 64, &Vs[buf][0] + tid * 8);
    if (tid < 128) gload_lds16(vsrc2 + (size_t)kt * 64, &Vs[buf][0] + 4096 + tid * 8);
  };

  bf16x8 aq[2][2];
#pragma unroll
  for (int m = 0; m < 2; ++m)
#pragma unroll
    for (int c = 0; c < 2; ++c)
      aq[m][c] = *(const bf16x8*)(qp + (size_t)(qw0 + (m << 4) + l15) * 64 + (c << 5) + (l4 << 3));

  f32x4 zo[2][5];
  float mrun[2] = {-INFINITY, -INFINITY};
#pragma unroll
  for (int m = 0; m < 2; ++m)
#pragma unroll
    for (int d = 0; d < 5; ++d) zo[m][d] = (f32x4){0.f, 0.f, 0.f, 0.f};

  u16* pw = &Ps[wid][0];

  stage(0, 0);
  __syncthreads();

  int cur = 0;
  for (int kt = 0; kt < nkt; ++kt) {
    if (kt + 1 < nkt) stage(cur ^ 1, kt + 1);

    if (kt <= ktmax) {
      const int k0 = kt << 6;
      const u16* kb_ = &Ks[cur][0];
      const u16* vb_ = &Vs[cur][0];
      f32x4 s[2][4];
#pragma unroll
      for (int m = 0; m < 2; ++m)
#pragma unroll
        for (int nf = 0; nf < 4; ++nf) s[m][nf] = (f32x4){0.f, 0.f, 0.f, 0.f};
#pragma unroll
      for (int nf = 0; nf < 4; ++nf) {
        const u16* kr = kb_ + ((nf << 4) + l15) * 64;
        const bf16x8 kf0 = *(const bf16x8*)(kr + ((l4 ^ swz) << 3));
        const bf16x8 kf1 = *(const bf16x8*)(kr + (((l4 + 4) ^ swz) << 3));
#pragma unroll
        for (int m = 0; m < 2; ++m) {
          s[m][nf] = __builtin_amdgcn_mfma_f32_16x16x32_bf16(kf0, aq[m][0], s[m][nf], 0, 0, 0);
          s[m][nf] = __builtin_amdgcn_mfma_f32_16x16x32_bf16(kf1, aq[m][1], s[m][nf], 0, 0, 0);
        }
      }
      if (kt == ktmax) {
#pragma unroll
        for (int m = 0; m < 2; ++m) {
          const int qtok = qw0 + (m << 4) + l15;
#pragma unroll
          for (int nf = 0; nf < 4; ++nf)
#pragma unroll
            for (int r = 0; r < 4; ++r) {
              const int ktok = k0 + (nf << 4) + (l4 << 2) + r;
              if (ktok > qtok) s[m][nf][r] = -INFINITY;
            }
        }
      }
#pragma unroll
      for (int m = 0; m < 2; ++m) {
        float mx = s[m][0][0];
#pragma unroll
        for (int nf = 0; nf < 4; ++nf)
#pragma unroll
          for (int r = 0; r < 4; ++r) mx = fmaxf(mx, s[m][nf][r]);
        mx = fmaxf(mx, __shfl_xor(mx, 16));
        mx = fmaxf(mx, __shfl_xor(mx, 32));
        if (__ballot(mx > mrun[m])) {
          const float mnew = fmaxf(mrun[m], mx);
          const float alpha = exp2f(mrun[m] - mnew);
          mrun[m] = mnew;
#pragma unroll
          for (int d = 0; d < 5; ++d) zo[m][d] *= alpha;
        }
        const int row = (m << 4) + l15;
#pragma unroll
        for (int nf = 0; nf < 4; ++nf) {
          f32x4 p;
#pragma unroll
          for (int r = 0; r < 4; ++r) p[r] = exp2f(s[m][nf][r] - mrun[m]);
          const int phys = ((nf << 1) + (l4 >> 1)) ^ swz;
          uint2 o; o.x = cvt2(p[0], p[1]); o.y = cvt2(p[2], p[3]);
          *(u32*)(pw + row * 64 + phys * 8 + ((l4 & 1) << 2)) = o.x;
          *(u32*)(pw + row * 64 + phys * 8 + ((l4 & 1) << 2) + 2) = o.y;
        }
      }
      bf16x8 pa[2][2];
#pragma unroll
      for (int m = 0; m < 2; ++m)
#pragma unroll
        for (int c = 0; c < 2; ++c) {
          const int phys = ((c << 2) + l4) ^ swz;
          pa[m][c] = *(const bf16x8*)(pw + ((m << 4) + l15) * 64 + phys * 8);
        }
#pragma unroll
      for (int d = 0; d < 5; ++d) {
        const u16* vr = vb_ + ((d << 4) + l15) * 64;
        const bf16x8 vf0 = *(const bf16x8*)(vr + ((l4 ^ swz) << 3));
        const bf16x8 vf1 = *(const bf16x8*)(vr + (((l4 + 4) ^ swz) << 3));
        zo[0][d] = __builtin_amdgcn_mfma_f32_16x16x32_bf16(vf0, pa[0][0], zo[0][d], 0, 0, 0);
        zo[0][d] = __builtin_amdgcn_mfma_f32_16x16x32_bf16(vf1, pa[0][1], zo[0][d], 0, 0, 0);
        zo[1][d] = __builtin_amdgcn_mfma_f32_16x16x32_bf16(vf0, pa[1][0], zo[1][d], 0, 0, 0);
        zo[1][d] = __builtin_amdgcn_mfma_f32_16x16x32_bf16(vf1, pa[1][1], zo[1][d], 0, 0, 0);
      }
    }
    __syncthreads();
    cur ^= 1;
  }

#pragma unroll
  for (int m = 0; m < 2; ++m) {
    const float sm = __shfl(zo[m][4][0], l15);
    const float inv = 1.0f / sm;
    const int q = qw0 + (m << 4) + l15;
#pragma unroll
    for (int d = 0; d < 4; ++d) {
      uint2 o;
      o.x = cvt2(zo[m][d][0] * inv, zo[m][d][1] * inv);
      o.y = cvt2(zo[m][d][2] * inv, zo[m][d][3] * inv);
      *(uint2*)(zb + (((size_t)b * SEQ + q) * 16 + h) * 64 + (d << 4) + (l4 << 2)) = o;
    }
  }
}

// ---------------- launch ----------------
extern "C" void kernel_launch(void* const* d_in, const int* in_sizes, int n_in,
                              void* d_out, int out_size, void* d_ws, size_t ws_size,
                              hipStream_t stream) {
  const float* x     = (const float*)d_in[0];
  const float* w_qkv = (const float*)d_in[1];
  const float* b_qkv = (const float*)d_in[2];
  const float* w_out = (const float*)d_in[3];
  const float* b_out = (const float*)d_in[4];
  float* out = (float*)d_out;

  char* ws = (char*)d_ws;
  u16* xb    = (u16*)ws;  ws += (size_t)MTOK * DM * 2;
  u16* wqkvT = (u16*)ws;  ws += (size_t)NQKV * DM * 2;
  u16* woutT = (u16*)ws;  ws += (size_t)DM * DM * 2;
  u16* qb    = (u16*)ws;  ws += (size_t)MTOK * DM * 2;
  u16* kb    = (u16*)ws;  ws += (size_t)MTOK * DM * 2;
  u16* vTb   = (u16*)ws;  ws += (size_t)64 * 80 * SEQ * 2;
  u16* zbuf  = (u16*)ws;  ws += (size_t)MTOK * DM * 2;

  cast_x_kernel<<<MTOK * DM / 1024, 256, 0, stream>>>(x, xb);
  transpose_cast_kernel<<<dim3(NQKV / 32, DM / 32), 256, 0, stream>>>(w_qkv, wqkvT, DM, NQKV);
  transpose_cast_kernel<<<dim3(DM / 32, DM / 32), 256, 0, stream>>>(w_out, woutT, DM, DM);
  fill_vpad_kernel<<<2048, 256, 0, stream>>>(vTb);

  gemm8_qkv_kernel<<<384, 512, 0, stream>>>(xb, wqkvT, b_qkv, qb, kb, vTb);

  attn_kernel<<<512, 512, 0, stream>>>(qb, kb, vTb, zbuf);

  gemm_out_kernel<<<dim3(DM / 128, MTOK / 128), 256, 0, stream>>>(
      zbuf, woutT, b_out, out, DM);
}

// Round 9
// 205.725 us; speedup vs baseline: 1.0880x; 1.0880x over previous
//
#include <hip/hip_runtime.h>
#include <hip/hip_bf16.h>

typedef unsigned short u16;
typedef unsigned int u32;
typedef short bf16x8 __attribute__((ext_vector_type(8)));
typedef float f32x4 __attribute__((ext_vector_type(4)));

#define DM 1024
#define SEQ 2048
#define MTOK 8192   // 4*2048
#define NQKV 3072

// 0.125 * log2(e): scores land in log2 domain -> exp2f is a single v_exp_f32
#define QSCALE 0.18033688011112042f

__device__ __forceinline__ u16 f2bf(float f) {
  union { float f; unsigned u; } a; a.f = f;
  unsigned r = a.u + 0x7FFFu + ((a.u >> 16) & 1u);
  return (u16)(r >> 16);
}

__device__ __forceinline__ u32 cvt2(float a, float b) {
  __hip_bfloat162 t = __float22bfloat162_rn(make_float2(a, b));
  u32 r; __builtin_memcpy(&r, &t, 4); return r;
}

__device__ __forceinline__ void gload_lds16(const u16* g, u16* l) {
  __builtin_amdgcn_global_load_lds(
      (const __attribute__((address_space(1))) unsigned int*)g,
      (__attribute__((address_space(3))) unsigned int*)l, 16, 0, 0);
}

// ---------------- cast x (fp32 -> bf16), vectorized ----------------
__global__ __launch_bounds__(256) void cast_x_kernel(const float* __restrict__ in,
                                                     u16* __restrict__ out) {
  int i = blockIdx.x * 256 + threadIdx.x;
  float4 v = ((const float4*)in)[i];
  ushort4 o;
  o.x = f2bf(v.x); o.y = f2bf(v.y); o.z = f2bf(v.z); o.w = f2bf(v.w);
  ((ushort4*)out)[i] = o;
}

// ---------------- transpose + cast: in [R][C] fp32 -> out [C][R] bf16 ----------------
__global__ __launch_bounds__(256) void transpose_cast_kernel(const float* __restrict__ in,
                                                             u16* __restrict__ out,
                                                             int R, int C) {
  __shared__ float tile[32][33];
  const int tx = threadIdx.x & 31, ty = threadIdx.x >> 5;
  const int r0 = blockIdx.y << 5, c0 = blockIdx.x << 5;
#pragma unroll
  for (int i = 0; i < 32; i += 8)
    tile[ty + i][tx] = in[(size_t)(r0 + ty + i) * C + (c0 + tx)];
  __syncthreads();
#pragma unroll
  for (int i = 0; i < 32; i += 8)
    out[(size_t)(c0 + ty + i) * R + (r0 + tx)] = f2bf(tile[tx][ty + i]);
}

// ---------------- fill V^T pad rows: row 64 = ones (row-sum row), 65..79 = 0 ----------
__global__ __launch_bounds__(256) void fill_vpad_kernel(u16* __restrict__ vT) {
  const int i = blockIdx.x * 256 + threadIdx.x;   // 524288 ushort4 slots
  const int col4 = i & (SEQ / 4 - 1);
  const int rowg = i >> 9;                        // bh*16 + r
  const int bh = rowg >> 4, r = rowg & 15;
  const u16 val = (r == 0) ? (u16)0x3F80 : (u16)0;
  ushort4 o; o.x = val; o.y = val; o.z = val; o.w = val;
  ((ushort4*)(vT + ((size_t)bh * 80 + 64 + r) * SEQ))[col4] = o;
}

// ========== GEMM (2-phase + prefetch): 128x128 tile, BK=64, dbuf LDS 64KB ==========
// A[M][1024] bf16 @ Bt[N][1024]^T. 4 waves (2x2), wave-tile 64x64.
// Per K-tile: issue stage(t+1) FIRST (global_load_lds, linear dest, pre-swizzled src),
// then 16 ds_read_b128 (chunk-XOR swizzled -> 2-way max) + 32 MFMA,
// then one __syncthreads() (vmcnt0+lgkmcnt0 drain) per tile. 2 blocks/CU co-resident.
// EPI=0: scatter q (pre-scaled), k, vT. EPI=1: fp32 out + bias.
template <int EPI>
__global__ __launch_bounds__(256, 2) void gemm2_kernel(
    const u16* __restrict__ A, const u16* __restrict__ Bt,
    const float* __restrict__ bias,
    u16* __restrict__ oq, u16* __restrict__ ok, u16* __restrict__ ovT,
    float* __restrict__ of, int N, int nbc) {
  __shared__ alignas(16) u16 As[2][128 * 64];   // 32 KB
  __shared__ alignas(16) u16 Bs[2][128 * 64];   // 32 KB

  const int tid = threadIdx.x, lane = tid & 63, wid = tid >> 6;
  const int wr = wid >> 1, wc = wid & 1;
  const int l15 = lane & 15, l4 = lane >> 4;
  const int swz = l15 & 7;

  // XCD-chunked bijective tile mapping (gridDim.x % 8 == 0); bcol varies fastest
  // within an XCD's chunk -> A row-panel (256 KB) stays L2-resident per XCD.
  const int cpx = gridDim.x >> 3;
  const int tile = (blockIdx.x & 7) * cpx + (blockIdx.x >> 3);
  const int row0 = (tile / nbc) << 7, col0 = (tile % nbc) << 7;

  // staging: 4 loads A + 4 loads B per thread per K-tile; dest linear (lane*16B),
  // source chunk pre-swizzled by row&7 (rule #21: swizzle source + reads, not dest).
  const int sr = tid >> 3;                              // 0..31
  const int scsw = ((tid & 7) ^ (sr & 7)) << 3;         // swizzled chunk (u16 offset)
  const u16* asrc = A + (size_t)(row0 + sr) * 1024 + scsw;
  const u16* bsrc = Bt + (size_t)(col0 + sr) * 1024 + scsw;

  auto stage = [&](int buf, int kt) {
#pragma unroll
    for (int j = 0; j < 4; ++j)
      gload_lds16(asrc + (size_t)(j << 5) * 1024 + (kt << 6),
                  &As[buf][0] + (j << 11) + tid * 8);
#pragma unroll
    for (int j = 0; j < 4; ++j)
      gload_lds16(bsrc + (size_t)(j << 5) * 1024 + (kt << 6),
                  &Bs[buf][0] + (j << 11) + tid * 8);
  };

  f32x4 acc[4][4];
#pragma unroll
  for (int m = 0; m < 4; ++m)
#pragma unroll
    for (int n = 0; n < 4; ++n) acc[m][n] = (f32x4){0.f, 0.f, 0.f, 0.f};

  stage(0, 0);
  __syncthreads();

  int cur = 0;
#pragma unroll 1
  for (int t = 0; t < 16; ++t) {
    if (t < 15) stage(cur ^ 1, t + 1);    // issue next-tile loads FIRST (T3-minimum)

    bf16x8 af[4][2], bfr[4][2];
    {
      const u16* base = &As[cur][0] + ((wr << 6) + l15) * 64;
#pragma unroll
      for (int mf = 0; mf < 4; ++mf)
#pragma unroll
        for (int ks = 0; ks < 2; ++ks)
          af[mf][ks] = *(const bf16x8*)(base + (mf << 4) * 64 + ((((ks << 2) + l4) ^ swz) << 3));
    }
    {
      const u16* base = &Bs[cur][0] + ((wc << 6) + l15) * 64;
#pragma unroll
      for (int nf = 0; nf < 4; ++nf)
#pragma unroll
        for (int ks = 0; ks < 2; ++ks)
          bfr[nf][ks] = *(const bf16x8*)(base + (nf << 4) * 64 + ((((ks << 2) + l4) ^ swz) << 3));
    }
#pragma unroll
    for (int ks = 0; ks < 2; ++ks)
#pragma unroll
      for (int mf = 0; mf < 4; ++mf)
#pragma unroll
        for (int nf = 0; nf < 4; ++nf)
          acc[mf][nf] = __builtin_amdgcn_mfma_f32_16x16x32_bf16(af[mf][ks], bfr[nf][ks],
                                                                acc[mf][nf], 0, 0, 0);
    __syncthreads();   // vmcnt(0)+lgkmcnt(0)+barrier: next buffer staged, reads done
    cur ^= 1;
  }

#pragma unroll
  for (int nf = 0; nf < 4; ++nf) {
    const int col = col0 + (wc << 6) + (nf << 4) + l15;
    const float bv = bias[col];
    if (EPI == 0) {
      const int sel = col >> 10;
      const int h = (col & 1023) >> 6;
      const int d = col & 63;
      const float scl = (sel == 0) ? QSCALE : 1.0f;
#pragma unroll
      for (int mf = 0; mf < 4; ++mf)
#pragma unroll
        for (int r = 0; r < 4; ++r) {
          const int row = row0 + (wr << 6) + (mf << 4) + (l4 << 2) + r;
          const int bb = row >> 11, s = row & 2047;
          const u16 v = f2bf((acc[mf][nf][r] + bv) * scl);
          const int bh = (bb << 4) + h;
          if (sel == 0)      oq[((size_t)bh * SEQ + s) * 64 + d] = v;
          else if (sel == 1) ok[((size_t)bh * SEQ + s) * 64 + d] = v;
          else               ovT[((size_t)bh * 80 + d) * SEQ + s] = v;
        }
    } else {
#pragma unroll
      for (int mf = 0; mf < 4; ++mf)
#pragma unroll
        for (int r = 0; r < 4; ++r) {
          const int row = row0 + (wr << 6) + (mf << 4) + (l4 << 2) + r;
          of[(size_t)row * N + col] = acc[mf][nf][r] + bv;
        }
    }
  }
}

// ---------------- flash attention: 8 waves/block, K/V staged in LDS -----------------
__global__ __launch_bounds__(512, 4) void attn_kernel(const u16* __restrict__ qb,
                                                      const u16* __restrict__ kbuf,
                                                      const u16* __restrict__ vT,
                                                      u16* __restrict__ zb) {
  __shared__ alignas(16) u16 Ks[2][64 * 64];   // 16 KB
  __shared__ alignas(16) u16 Vs[2][80 * 64];   // 20 KB
  __shared__ alignas(16) u16 Ps[8][32 * 64];   // 32 KB

  const int bid = blockIdx.x;
  const int xcd = bid & 7;
  const int idx = bid >> 3;
  const int bh = (xcd << 3) | (idx & 7);        // 8 bh per XCD
  const int qpart = idx >> 3;                   // 0..7
  const int qseg = (qpart < 4) ? (7 - qpart) : (qpart - 4);  // CU pairs sum to 7
  const int b = bh >> 4, h = bh & 15;

  const int tid = threadIdx.x;
  const int lane = tid & 63, wid = tid >> 6;
  const int l15 = lane & 15, l4 = lane >> 4;
  const int swz = l15 & 7;

  const u16* qp = qb + (size_t)bh * SEQ * 64;
  const u16* kp = kbuf + (size_t)bh * SEQ * 64;
  const u16* vp = vT + (size_t)bh * 80 * SEQ;

  const int qw0 = qseg * 256 + (wid << 5);      // this wave's first q row
  const int nkt = (qseg + 1) << 2;              // block k-tiles
  const int ktmax = (qseg << 2) + (wid >> 1);   // this wave's diagonal tile

  const int srow = tid >> 3, schk = tid & 7;
  const u16* ksrc  = kp + (size_t)srow * 64 + ((schk ^ (srow & 7)) << 3);
  const u16* vsrc  = vp + (size_t)srow * SEQ + ((schk ^ (srow & 7)) << 3);
  const u16* vsrc2 = vp + (size_t)(64 + srow) * SEQ + ((schk ^ (srow & 7)) << 3);

  auto stage = [&](int buf, int kt) {
    gload_lds16(ksrc + (size_t)kt * 4096, &Ks[buf][0] + tid * 8);
    gload_lds16(vsrc + (size_t)kt * 64, &Vs[buf][0] + tid * 8);
    if (tid < 128) gload_lds16(vsrc2 + (size_t)kt * 64, &Vs[buf][0] + 4096 + tid * 8);
  };

  bf16x8 aq[2][2];
#pragma unroll
  for (int m = 0; m < 2; ++m)
#pragma unroll
    for (int c = 0; c < 2; ++c)
      aq[m][c] = *(const bf16x8*)(qp + (size_t)(qw0 + (m << 4) + l15) * 64 + (c << 5) + (l4 << 3));

  f32x4 zo[2][5];
  float mrun[2] = {-INFINITY, -INFINITY};
#pragma unroll
  for (int m = 0; m < 2; ++m)
#pragma unroll
    for (int d = 0; d < 5; ++d) zo[m][d] = (f32x4){0.f, 0.f, 0.f, 0.f};

  u16* pw = &Ps[wid][0];

  stage(0, 0);
  __syncthreads();

  int cur = 0;
  for (int kt = 0; kt < nkt; ++kt) {
    if (kt + 1 < nkt) stage(cur ^ 1, kt + 1);

    if (kt <= ktmax) {
      const int k0 = kt << 6;
      const u16* kb_ = &Ks[cur][0];
      const u16* vb_ = &Vs[cur][0];
      f32x4 s[2][4];
#pragma unroll
      for (int m = 0; m < 2; ++m)
#pragma unroll
        for (int nf = 0; nf < 4; ++nf) s[m][nf] = (f32x4){0.f, 0.f, 0.f, 0.f};
#pragma unroll
      for (int nf = 0; nf < 4; ++nf) {
        const u16* kr = kb_ + ((nf << 4) + l15) * 64;
        const bf16x8 kf0 = *(const bf16x8*)(kr + ((l4 ^ swz) << 3));
        const bf16x8 kf1 = *(const bf16x8*)(kr + (((l4 + 4) ^ swz) << 3));
#pragma unroll
        for (int m = 0; m < 2; ++m) {
          s[m][nf] = __builtin_amdgcn_mfma_f32_16x16x32_bf16(kf0, aq[m][0], s[m][nf], 0, 0, 0);
          s[m][nf] = __builtin_amdgcn_mfma_f32_16x16x32_bf16(kf1, aq[m][1], s[m][nf], 0, 0, 0);
        }
      }
      if (kt == ktmax) {
#pragma unroll
        for (int m = 0; m < 2; ++m) {
          const int qtok = qw0 + (m << 4) + l15;
#pragma unroll
          for (int nf = 0; nf < 4; ++nf)
#pragma unroll
            for (int r = 0; r < 4; ++r) {
              const int ktok = k0 + (nf << 4) + (l4 << 2) + r;
              if (ktok > qtok) s[m][nf][r] = -INFINITY;
            }
        }
      }
#pragma unroll
      for (int m = 0; m < 2; ++m) {
        float mx = s[m][0][0];
#pragma unroll
        for (int nf = 0; nf < 4; ++nf)
#pragma unroll
          for (int r = 0; r < 4; ++r) mx = fmaxf(mx, s[m][nf][r]);
        mx = fmaxf(mx, __shfl_xor(mx, 16));
        mx = fmaxf(mx, __shfl_xor(mx, 32));
        if (__ballot(mx > mrun[m])) {
          const float mnew = fmaxf(mrun[m], mx);
          const float alpha = exp2f(mrun[m] - mnew);
          mrun[m] = mnew;
#pragma unroll
          for (int d = 0; d < 5; ++d) zo[m][d] *= alpha;
        }
        const int row = (m << 4) + l15;
#pragma unroll
        for (int nf = 0; nf < 4; ++nf) {
          f32x4 p;
#pragma unroll
          for (int r = 0; r < 4; ++r) p[r] = exp2f(s[m][nf][r] - mrun[m]);
          const int phys = ((nf << 1) + (l4 >> 1)) ^ swz;
          uint2 o; o.x = cvt2(p[0], p[1]); o.y = cvt2(p[2], p[3]);
          *(u32*)(pw + row * 64 + phys * 8 + ((l4 & 1) << 2)) = o.x;
          *(u32*)(pw + row * 64 + phys * 8 + ((l4 & 1) << 2) + 2) = o.y;
        }
      }
      bf16x8 pa[2][2];
#pragma unroll
      for (int m = 0; m < 2; ++m)
#pragma unroll
        for (int c = 0; c < 2; ++c) {
          const int phys = ((c << 2) + l4) ^ swz;
          pa[m][c] = *(const bf16x8*)(pw + ((m << 4) + l15) * 64 + phys * 8);
        }
#pragma unroll
      for (int d = 0; d < 5; ++d) {
        const u16* vr = vb_ + ((d << 4) + l15) * 64;
        const bf16x8 vf0 = *(const bf16x8*)(vr + ((l4 ^ swz) << 3));
        const bf16x8 vf1 = *(const bf16x8*)(vr + (((l4 + 4) ^ swz) << 3));
        zo[0][d] = __builtin_amdgcn_mfma_f32_16x16x32_bf16(vf0, pa[0][0], zo[0][d], 0, 0, 0);
        zo[0][d] = __builtin_amdgcn_mfma_f32_16x16x32_bf16(vf1, pa[0][1], zo[0][d], 0, 0, 0);
        zo[1][d] = __builtin_amdgcn_mfma_f32_16x16x32_bf16(vf0, pa[1][0], zo[1][d], 0, 0, 0);
        zo[1][d] = __builtin_amdgcn_mfma_f32_16x16x32_bf16(vf1, pa[1][1], zo[1][d], 0, 0, 0);
      }
    }
    __syncthreads();
    cur ^= 1;
  }

#pragma unroll
  for (int m = 0; m < 2; ++m) {
    const float sm = __shfl(zo[m][4][0], l15);
    const float inv = 1.0f / sm;
    const int q = qw0 + (m << 4) + l15;
#pragma unroll
    for (int d = 0; d < 4; ++d) {
      uint2 o;
      o.x = cvt2(zo[m][d][0] * inv, zo[m][d][1] * inv);
      o.y = cvt2(zo[m][d][2] * inv, zo[m][d][3] * inv);
      *(uint2*)(zb + (((size_t)b * SEQ + q) * 16 + h) * 64 + (d << 4) + (l4 << 2)) = o;
    }
  }
}

// ---------------- launch ----------------
extern "C" void kernel_launch(void* const* d_in, const int* in_sizes, int n_in,
                              void* d_out, int out_size, void* d_ws, size_t ws_size,
                              hipStream_t stream) {
  const float* x     = (const float*)d_in[0];
  const float* w_qkv = (const float*)d_in[1];
  const float* b_qkv = (const float*)d_in[2];
  const float* w_out = (const float*)d_in[3];
  const float* b_out = (const float*)d_in[4];
  float* out = (float*)d_out;

  char* ws = (char*)d_ws;
  u16* xb    = (u16*)ws;  ws += (size_t)MTOK * DM * 2;
  u16* wqkvT = (u16*)ws;  ws += (size_t)NQKV * DM * 2;
  u16* woutT = (u16*)ws;  ws += (size_t)DM * DM * 2;
  u16* qb    = (u16*)ws;  ws += (size_t)MTOK * DM * 2;
  u16* kb    = (u16*)ws;  ws += (size_t)MTOK * DM * 2;
  u16* vTb   = (u16*)ws;  ws += (size_t)64 * 80 * SEQ * 2;
  u16* zbuf  = (u16*)ws;  ws += (size_t)MTOK * DM * 2;

  cast_x_kernel<<<MTOK * DM / 1024, 256, 0, stream>>>(x, xb);
  transpose_cast_kernel<<<dim3(NQKV / 32, DM / 32), 256, 0, stream>>>(w_qkv, wqkvT, DM, NQKV);
  transpose_cast_kernel<<<dim3(DM / 32, DM / 32), 256, 0, stream>>>(w_out, woutT, DM, DM);
  fill_vpad_kernel<<<2048, 256, 0, stream>>>(vTb);

  gemm2_kernel<0><<<1536, 256, 0, stream>>>(xb, wqkvT, b_qkv, qb, kb, vTb, nullptr, NQKV, 24);

  attn_kernel<<<512, 512, 0, stream>>>(qb, kb, vTb, zbuf);

  gemm2_kernel<1><<<512, 256, 0, stream>>>(zbuf, woutT, b_out, nullptr, nullptr, nullptr, out, DM, 8);
}

// Round 10
// 199.549 us; speedup vs baseline: 1.1217x; 1.0309x over previous
//
#include <hip/hip_runtime.h>
#include <hip/hip_bf16.h>

typedef unsigned short u16;
typedef unsigned int u32;
typedef short bf16x8 __attribute__((ext_vector_type(8)));
typedef float f32x4 __attribute__((ext_vector_type(4)));

#define DM 1024
#define SEQ 2048
#define MTOK 8192   // 4*2048
#define NQKV 3072

// 0.125 * log2(e): scores land in log2 domain -> exp2f is a single v_exp_f32
#define QSCALE 0.18033688011112042f

#define BAR() __builtin_amdgcn_s_barrier()
#define VMW(n) asm volatile("s_waitcnt vmcnt(" #n ")" ::: "memory")
#define LGKW() asm volatile("s_waitcnt lgkmcnt(0)" ::: "memory")

__device__ __forceinline__ u16 f2bf(float f) {
  union { float f; unsigned u; } a; a.f = f;
  unsigned r = a.u + 0x7FFFu + ((a.u >> 16) & 1u);
  return (u16)(r >> 16);
}

__device__ __forceinline__ u32 cvt2(float a, float b) {
  __hip_bfloat162 t = __float22bfloat162_rn(make_float2(a, b));
  u32 r; __builtin_memcpy(&r, &t, 4); return r;
}

__device__ __forceinline__ void gload_lds16(const u16* g, u16* l) {
  __builtin_amdgcn_global_load_lds(
      (const __attribute__((address_space(1))) unsigned int*)g,
      (__attribute__((address_space(3))) unsigned int*)l, 16, 0, 0);
}

// ---------------- cast x (fp32 -> bf16), vectorized ----------------
__global__ __launch_bounds__(256) void cast_x_kernel(const float* __restrict__ in,
                                                     u16* __restrict__ out) {
  int i = blockIdx.x * 256 + threadIdx.x;
  float4 v = ((const float4*)in)[i];
  ushort4 o;
  o.x = f2bf(v.x); o.y = f2bf(v.y); o.z = f2bf(v.z); o.w = f2bf(v.w);
  ((ushort4*)out)[i] = o;
}

// ---------------- transpose + cast: in [R][C] fp32 -> out [C][R] bf16 ----------------
__global__ __launch_bounds__(256) void transpose_cast_kernel(const float* __restrict__ in,
                                                             u16* __restrict__ out,
                                                             int R, int C) {
  __shared__ float tile[32][33];
  const int tx = threadIdx.x & 31, ty = threadIdx.x >> 5;
  const int r0 = blockIdx.y << 5, c0 = blockIdx.x << 5;
#pragma unroll
  for (int i = 0; i < 32; i += 8)
    tile[ty + i][tx] = in[(size_t)(r0 + ty + i) * C + (c0 + tx)];
  __syncthreads();
#pragma unroll
  for (int i = 0; i < 32; i += 8)
    out[(size_t)(c0 + ty + i) * R + (r0 + tx)] = f2bf(tile[tx][ty + i]);
}

// ---------------- fill V^T pad rows: row 64 = ones (row-sum row), 65..79 = 0 ----------
__global__ __launch_bounds__(256) void fill_vpad_kernel(u16* __restrict__ vT) {
  const int i = blockIdx.x * 256 + threadIdx.x;   // 524288 ushort4 slots
  const int col4 = i & (SEQ / 4 - 1);
  const int rowg = i >> 9;                        // bh*16 + r
  const int bh = rowg >> 4, r = rowg & 15;
  const u16 val = (r == 0) ? (u16)0x3F80 : (u16)0;
  ushort4 o; o.x = val; o.y = val; o.z = val; o.w = val;
  ((ushort4*)(vT + ((size_t)bh * 80 + 64 + r) * SEQ))[col4] = o;
}

// ========= GEMM: 128x128 tile, BK=64, depth-2 counted-vmcnt pipeline =========
// A[M][1024] bf16 @ Bt[N][1024]^T. 4 waves (2x2), wave-tile 64x64. K = 16 tiles.
// Prologue stages tiles 0,1. Per iteration:
//   vmcnt(8) -> barrier        (tile t landed; tile t+1's 8 loads stay in flight)
//   16x ds_read_b128 (XOR-swizzled); lgkmcnt(0)   (regs loaded -> WAR-safe)
//   barrier                    (all waves done reading buf[cur])
//   stage(buf[cur], t+2)       (8 global_load_lds, linear dest, pre-swz source)
//   setprio(1); 32x MFMA; setprio(0)
// No vmcnt(0) drain until the final tile. Loads get ~2 iterations to complete.
// XCD map: row-panel fastest within XCD -> ~2MB A + 2MB B co-resident per L2.
template <int EPI>
__global__ __launch_bounds__(256, 2) void gemm2_kernel(
    const u16* __restrict__ A, const u16* __restrict__ Bt,
    const float* __restrict__ bias,
    u16* __restrict__ oq, u16* __restrict__ ok, u16* __restrict__ ovT,
    float* __restrict__ of, int N) {
  __shared__ alignas(16) u16 As[2][128 * 64];   // 32 KB
  __shared__ alignas(16) u16 Bs[2][128 * 64];   // 32 KB

  const int tid = threadIdx.x, lane = tid & 63, wid = tid >> 6;
  const int wr = wid >> 1, wc = wid & 1;
  const int l15 = lane & 15, l4 = lane >> 4;
  const int swz = l15 & 7;

  // XCD-chunked mapping: 8 consecutive row-panels per XCD, row varies fastest.
  const int xcd = blockIdx.x & 7, idx = blockIdx.x >> 3;
  const int row0 = ((xcd << 3) + (idx & 7)) << 7;
  const int col0 = (idx >> 3) << 7;

  // staging: 4 loads A + 4 loads B per thread per K-tile; dest linear (tid*16B),
  // source chunk pre-swizzled by row&7 (rule #21).
  const int sr = tid >> 3;                              // 0..31
  const int scsw = ((tid & 7) ^ (sr & 7)) << 3;         // swizzled chunk (u16 offset)
  const u16* asrc = A + (size_t)(row0 + sr) * 1024 + scsw;
  const u16* bsrc = Bt + (size_t)(col0 + sr) * 1024 + scsw;

  auto stage = [&](int buf, int kt) {
#pragma unroll
    for (int j = 0; j < 4; ++j)
      gload_lds16(asrc + (size_t)(j << 5) * 1024 + (kt << 6),
                  &As[buf][0] + (j << 11) + tid * 8);
#pragma unroll
    for (int j = 0; j < 4; ++j)
      gload_lds16(bsrc + (size_t)(j << 5) * 1024 + (kt << 6),
                  &Bs[buf][0] + (j << 11) + tid * 8);
  };

  f32x4 acc[4][4];
#pragma unroll
  for (int m = 0; m < 4; ++m)
#pragma unroll
    for (int n = 0; n < 4; ++n) acc[m][n] = (f32x4){0.f, 0.f, 0.f, 0.f};

  stage(0, 0);
  stage(1, 1);

  int cur = 0;
#pragma unroll 1
  for (int t = 0; t < 16; ++t) {
    if (t < 15) { VMW(8); } else { VMW(0); }   // tile t landed; t+1 stays in flight
    BAR();

    bf16x8 af[4][2], bfr[4][2];
    {
      const u16* base = &As[cur][0] + ((wr << 6) + l15) * 64;
#pragma unroll
      for (int mf = 0; mf < 4; ++mf)
#pragma unroll
        for (int ks = 0; ks < 2; ++ks)
          af[mf][ks] = *(const bf16x8*)(base + (mf << 4) * 64 + ((((ks << 2) + l4) ^ swz) << 3));
    }
    {
      const u16* base = &Bs[cur][0] + ((wc << 6) + l15) * 64;
#pragma unroll
      for (int nf = 0; nf < 4; ++nf)
#pragma unroll
        for (int ks = 0; ks < 2; ++ks)
          bfr[nf][ks] = *(const bf16x8*)(base + (nf << 4) * 64 + ((((ks << 2) + l4) ^ swz) << 3));
    }
    LGKW();            // frags in registers -> safe to overwrite buf[cur] after barrier
    BAR();
    if (t < 14) stage(cur, t + 2);   // refill the buffer we just consumed

    __builtin_amdgcn_s_setprio(1);
#pragma unroll
    for (int ks = 0; ks < 2; ++ks)
#pragma unroll
      for (int mf = 0; mf < 4; ++mf)
#pragma unroll
        for (int nf = 0; nf < 4; ++nf)
          acc[mf][nf] = __builtin_amdgcn_mfma_f32_16x16x32_bf16(af[mf][ks], bfr[nf][ks],
                                                                acc[mf][nf], 0, 0, 0);
    __builtin_amdgcn_s_setprio(0);
    cur ^= 1;
  }

#pragma unroll
  for (int nf = 0; nf < 4; ++nf) {
    const int col = col0 + (wc << 6) + (nf << 4) + l15;
    const float bv = bias[col];
    if (EPI == 0) {
      const int sel = col >> 10;
      const int h = (col & 1023) >> 6;
      const int d = col & 63;
      const float scl = (sel == 0) ? QSCALE : 1.0f;
#pragma unroll
      for (int mf = 0; mf < 4; ++mf)
#pragma unroll
        for (int r = 0; r < 4; ++r) {
          const int row = row0 + (wr << 6) + (mf << 4) + (l4 << 2) + r;
          const int bb = row >> 11, s = row & 2047;
          const u16 v = f2bf((acc[mf][nf][r] + bv) * scl);
          const int bh = (bb << 4) + h;
          if (sel == 0)      oq[((size_t)bh * SEQ + s) * 64 + d] = v;
          else if (sel == 1) ok[((size_t)bh * SEQ + s) * 64 + d] = v;
          else               ovT[((size_t)bh * 80 + d) * SEQ + s] = v;
        }
    } else {
#pragma unroll
      for (int mf = 0; mf < 4; ++mf)
#pragma unroll
        for (int r = 0; r < 4; ++r) {
          const int row = row0 + (wr << 6) + (mf << 4) + (l4 << 2) + r;
          of[(size_t)row * N + col] = acc[mf][nf][r] + bv;
        }
    }
  }
}

// ---------------- flash attention: 8 waves/block, K/V staged in LDS -----------------
__global__ __launch_bounds__(512, 4) void attn_kernel(const u16* __restrict__ qb,
                                                      const u16* __restrict__ kbuf,
                                                      const u16* __restrict__ vT,
                                                      u16* __restrict__ zb) {
  __shared__ alignas(16) u16 Ks[2][64 * 64];   // 16 KB
  __shared__ alignas(16) u16 Vs[2][80 * 64];   // 20 KB
  __shared__ alignas(16) u16 Ps[8][32 * 64];   // 32 KB

  const int bid = blockIdx.x;
  const int xcd = bid & 7;
  const int idx = bid >> 3;
  const int bh = (xcd << 3) | (idx & 7);        // 8 bh per XCD
  const int qpart = idx >> 3;                   // 0..7
  const int qseg = (qpart < 4) ? (7 - qpart) : (qpart - 4);  // CU pairs sum to 7
  const int b = bh >> 4, h = bh & 15;

  const int tid = threadIdx.x;
  const int lane = tid & 63, wid = tid >> 6;
  const int l15 = lane & 15, l4 = lane >> 4;
  const int swz = l15 & 7;

  const u16* qp = qb + (size_t)bh * SEQ * 64;
  const u16* kp = kbuf + (size_t)bh * SEQ * 64;
  const u16* vp = vT + (size_t)bh * 80 * SEQ;

  const int qw0 = qseg * 256 + (wid << 5);      // this wave's first q row
  const int nkt = (qseg + 1) << 2;              // block k-tiles
  const int ktmax = (qseg << 2) + (wid >> 1);   // this wave's diagonal tile

  const int srow = tid >> 3, schk = tid & 7;
  const u16* ksrc  = kp + (size_t)srow * 64 + ((schk ^ (srow & 7)) << 3);
  const u16* vsrc  = vp + (size_t)srow * SEQ + ((schk ^ (srow & 7)) << 3);
  const u16* vsrc2 = vp + (size_t)(64 + srow) * SEQ + ((schk ^ (srow & 7)) << 3);

  auto stage = [&](int buf, int kt) {
    gload_lds16(ksrc + (size_t)kt * 4096, &Ks[buf][0] + tid * 8);
    gload_lds16(vsrc + (size_t)kt * 64, &Vs[buf][0] + tid * 8);
    if (tid < 128) gload_lds16(vsrc2 + (size_t)kt * 64, &Vs[buf][0] + 4096 + tid * 8);
  };

  bf16x8 aq[2][2];
#pragma unroll
  for (int m = 0; m < 2; ++m)
#pragma unroll
    for (int c = 0; c < 2; ++c)
      aq[m][c] = *(const bf16x8*)(qp + (size_t)(qw0 + (m << 4) + l15) * 64 + (c << 5) + (l4 << 3));

  f32x4 zo[2][5];
  float mrun[2] = {-INFINITY, -INFINITY};
#pragma unroll
  for (int m = 0; m < 2; ++m)
#pragma unroll
    for (int d = 0; d < 5; ++d) zo[m][d] = (f32x4){0.f, 0.f, 0.f, 0.f};

  u16* pw = &Ps[wid][0];

  stage(0, 0);
  __syncthreads();

  int cur = 0;
  for (int kt = 0; kt < nkt; ++kt) {
    if (kt + 1 < nkt) stage(cur ^ 1, kt + 1);

    if (kt <= ktmax) {
      const int k0 = kt << 6;
      const u16* kb_ = &Ks[cur][0];
      const u16* vb_ = &Vs[cur][0];
      f32x4 s[2][4];
#pragma unroll
      for (int m = 0; m < 2; ++m)
#pragma unroll
        for (int nf = 0; nf < 4; ++nf) s[m][nf] = (f32x4){0.f, 0.f, 0.f, 0.f};
#pragma unroll
      for (int nf = 0; nf < 4; ++nf) {
        const u16* kr = kb_ + ((nf << 4) + l15) * 64;
        const bf16x8 kf0 = *(const bf16x8*)(kr + ((l4 ^ swz) << 3));
        const bf16x8 kf1 = *(const bf16x8*)(kr + (((l4 + 4) ^ swz) << 3));
#pragma unroll
        for (int m = 0; m < 2; ++m) {
          s[m][nf] = __builtin_amdgcn_mfma_f32_16x16x32_bf16(kf0, aq[m][0], s[m][nf], 0, 0, 0);
          s[m][nf] = __builtin_amdgcn_mfma_f32_16x16x32_bf16(kf1, aq[m][1], s[m][nf], 0, 0, 0);
        }
      }
      if (kt == ktmax) {
#pragma unroll
        for (int m = 0; m < 2; ++m) {
          const int qtok = qw0 + (m << 4) + l15;
#pragma unroll
          for (int nf = 0; nf < 4; ++nf)
#pragma unroll
            for (int r = 0; r < 4; ++r) {
              const int ktok = k0 + (nf << 4) + (l4 << 2) + r;
              if (ktok > qtok) s[m][nf][r] = -INFINITY;
            }
        }
      }
#pragma unroll
      for (int m = 0; m < 2; ++m) {
        float mx = s[m][0][0];
#pragma unroll
        for (int nf = 0; nf < 4; ++nf)
#pragma unroll
          for (int r = 0; r < 4; ++r) mx = fmaxf(mx, s[m][nf][r]);
        mx = fmaxf(mx, __shfl_xor(mx, 16));
        mx = fmaxf(mx, __shfl_xor(mx, 32));
        if (__ballot(mx > mrun[m])) {
          const float mnew = fmaxf(mrun[m], mx);
          const float alpha = exp2f(mrun[m] - mnew);
          mrun[m] = mnew;
#pragma unroll
          for (int d = 0; d < 5; ++d) zo[m][d] *= alpha;
        }
        const int row = (m << 4) + l15;
#pragma unroll
        for (int nf = 0; nf < 4; ++nf) {
          f32x4 p;
#pragma unroll
          for (int r = 0; r < 4; ++r) p[r] = exp2f(s[m][nf][r] - mrun[m]);
          const int phys = ((nf << 1) + (l4 >> 1)) ^ swz;
          uint2 o; o.x = cvt2(p[0], p[1]); o.y = cvt2(p[2], p[3]);
          *(u32*)(pw + row * 64 + phys * 8 + ((l4 & 1) << 2)) = o.x;
          *(u32*)(pw + row * 64 + phys * 8 + ((l4 & 1) << 2) + 2) = o.y;
        }
      }
      bf16x8 pa[2][2];
#pragma unroll
      for (int m = 0; m < 2; ++m)
#pragma unroll
        for (int c = 0; c < 2; ++c) {
          const int phys = ((c << 2) + l4) ^ swz;
          pa[m][c] = *(const bf16x8*)(pw + ((m << 4) + l15) * 64 + phys * 8);
        }
#pragma unroll
      for (int d = 0; d < 5; ++d) {
        const u16* vr = vb_ + ((d << 4) + l15) * 64;
        const bf16x8 vf0 = *(const bf16x8*)(vr + ((l4 ^ swz) << 3));
        const bf16x8 vf1 = *(const bf16x8*)(vr + (((l4 + 4) ^ swz) << 3));
        zo[0][d] = __builtin_amdgcn_mfma_f32_16x16x32_bf16(vf0, pa[0][0], zo[0][d], 0, 0, 0);
        zo[0][d] = __builtin_amdgcn_mfma_f32_16x16x32_bf16(vf1, pa[0][1], zo[0][d], 0, 0, 0);
        zo[1][d] = __builtin_amdgcn_mfma_f32_16x16x32_bf16(vf0, pa[1][0], zo[1][d], 0, 0, 0);
        zo[1][d] = __builtin_amdgcn_mfma_f32_16x16x32_bf16(vf1, pa[1][1], zo[1][d], 0, 0, 0);
      }
    }
    __syncthreads();
    cur ^= 1;
  }

#pragma unroll
  for (int m = 0; m < 2; ++m) {
    const float sm = __shfl(zo[m][4][0], l15);
    const float inv = 1.0f / sm;
    const int q = qw0 + (m << 4) + l15;
#pragma unroll
    for (int d = 0; d < 4; ++d) {
      uint2 o;
      o.x = cvt2(zo[m][d][0] * inv, zo[m][d][1] * inv);
      o.y = cvt2(zo[m][d][2] * inv, zo[m][d][3] * inv);
      *(uint2*)(zb + (((size_t)b * SEQ + q) * 16 + h) * 64 + (d << 4) + (l4 << 2)) = o;
    }
  }
}

// ---------------- launch ----------------
extern "C" void kernel_launch(void* const* d_in, const int* in_sizes, int n_in,
                              void* d_out, int out_size, void* d_ws, size_t ws_size,
                              hipStream_t stream) {
  const float* x     = (const float*)d_in[0];
  const float* w_qkv = (const float*)d_in[1];
  const float* b_qkv = (const float*)d_in[2];
  const float* w_out = (const float*)d_in[3];
  const float* b_out = (const float*)d_in[4];
  float* out = (float*)d_out;

  char* ws = (char*)d_ws;
  u16* xb    = (u16*)ws;  ws += (size_t)MTOK * DM * 2;
  u16* wqkvT = (u16*)ws;  ws += (size_t)NQKV * DM * 2;
  u16* woutT = (u16*)ws;  ws += (size_t)DM * DM * 2;
  u16* qb    = (u16*)ws;  ws += (size_t)MTOK * DM * 2;
  u16* kb    = (u16*)ws;  ws += (size_t)MTOK * DM * 2;
  u16* vTb   = (u16*)ws;  ws += (size_t)64 * 80 * SEQ * 2;
  u16* zbuf  = (u16*)ws;  ws += (size_t)MTOK * DM * 2;

  cast_x_kernel<<<MTOK * DM / 1024, 256, 0, stream>>>(x, xb);
  transpose_cast_kernel<<<dim3(NQKV / 32, DM / 32), 256, 0, stream>>>(w_qkv, wqkvT, DM, NQKV);
  transpose_cast_kernel<<<dim3(DM / 32, DM / 32), 256, 0, stream>>>(w_out, woutT, DM, DM);
  fill_vpad_kernel<<<2048, 256, 0, stream>>>(vTb);

  gemm2_kernel<0><<<1536, 256, 0, stream>>>(xb, wqkvT, b_qkv, qb, kb, vTb, nullptr, NQKV);

  attn_kernel<<<512, 512, 0, stream>>>(qb, kb, vTb, zbuf);

  gemm2_kernel<1><<<512, 256, 0, stream>>>(zbuf, woutT, b_out, nullptr, nullptr, nullptr, out, DM);
}